// Round 6
// baseline (199.033 us; speedup 1.0000x reference)
//
#include <hip/hip_runtime.h>

// ---------------------------------------------------------------------------
// Block-sparse linear  y = x @ W^T + bias  on MI355X (gfx950)
// Round 8: first variant to combine ALL THREE previously-isolated wins:
//   (a) 6 wgs/CU (r7: proven resident, 24KB LDS, VGPR<=85)
//   (b) counted vmcnt, never 0 in-loop (T4): k-split double buffer -- each
//       64-k block done as two 32-k half-steps of 12KB, so 2 buffers fit in
//       the SAME 24KB; loop = stage(t+1); vmcnt(3); barrier; compute(t);
//       barrier. stage(t) gets compute+2 barriers+issue of slack.
//   (c) conflict-free UNSWIZZLED LDS: for 64B rows (32-col tiles) the bank
//       slot is (row&1, chunk) -- row parity spreads banks, so fragment
//       reads are uniform 8 lanes/slot with NO swizzle. (r4's conflict was
//       introduced BY its swizzle: c=q^(m&3) collapses parity-0 lanes onto
//       2 slots = 4-way.)
// pk-list cached in LDS so in-loop vmem ops are EXACTLY 3 global_load_lds
// per wave per half-step (keeps vmcnt counts exact).
// Ledger: r2/r7=58us (drain-per-step, 4 resp 6 wgs/CU -- occupancy alone
// moved nothing), r3=95 (2 fat wgs), r4=77 (self-inflicted conflicts+drain),
// r5=132 (no LDS), r6=92 (A-direct FETCH bloat). Real MFMA-pipe util ~7%.
// ---------------------------------------------------------------------------

typedef __attribute__((ext_vector_type(8))) short bf16x8;   // MFMA A/B frag
typedef __attribute__((ext_vector_type(8))) unsigned short u16x8;
typedef __attribute__((ext_vector_type(4))) float f32x4;     // MFMA C/D frag

#define N_ROWS 4096
#define IN_DIM 4096
#define OUT_DIM 4096
#define K_BLOCKS 1024
#define NT 128            // rows per workgroup (4 waves x 32 rows)
#define PK_STRIDE 256     // max blocks per row-block we store (realistic max ~35)
#define AOFF 4096         // ushorts per A half-buffer (128 rows x 32 cols)
#define BOFF 2048         // ushorts per B half-buffer (64 rows x 32 cols)

// fp32 -> bf16 round-to-nearest-even
__device__ static inline unsigned short f2bf(float f) {
    unsigned u = __float_as_uint(f);
    u += 0x7FFFu + ((u >> 16) & 1u);
    return (unsigned short)(u >> 16);
}

__device__ static inline void async_copy16(const void* g, void* l) {
    __builtin_amdgcn_global_load_lds(
        (const __attribute__((address_space(1))) void*)g,
        (__attribute__((address_space(3))) void*)l, 16, 0, 0);
}

// --- prep: convert x (16M f32) + blocks (4M f32) to bf16, AND build CSR ----
// Blocks 0..10239 convert (each thread 8 floats); block 10240 builds the
// CSR + descending-count (LPT) schedule. Unchanged from r4-r7 (verified).
__global__ void bsl_prep(const float* __restrict__ x,
                         const float* __restrict__ blocks,
                         unsigned short* __restrict__ xb,
                         unsigned short* __restrict__ bb,
                         const int* __restrict__ row_idx,
                         const int* __restrict__ col_idx,
                         int* __restrict__ counts,
                         int* __restrict__ sched,
                         int* __restrict__ csr_pk) {
    if (blockIdx.x == 10240) {
        __shared__ int cnt_s[64];
        __shared__ int sorted_s[64];
        const int t = threadIdx.x;
        if (t < 64) cnt_s[t] = 0;
        __syncthreads();
#pragma unroll
        for (int i = 0; i < 4; ++i) {
            const int k = t + i * 256;           // 0..1023
            const int r = row_idx[k];
            const int rank = atomicAdd(&cnt_s[r], 1);
            if (rank < PK_STRIDE) csr_pk[r * PK_STRIDE + rank] = (k << 6) | col_idx[k];
        }
        __syncthreads();
        if (t < 64) {
            const int mc = cnt_s[t];
            counts[t] = mc;
            int pos = 0;
            for (int j = 0; j < 64; ++j) {
                const int cj = cnt_s[j];
                pos += (cj > mc || (cj == mc && j < t)) ? 1 : 0;
            }
            sorted_s[pos] = t;                   // descending by count
        }
        __syncthreads();
        if (t < 64) sched[t] = sorted_s[t];      // heavy row-blocks first (LPT)
        return;
    }
    // ---- convert ----
    long t = (long)blockIdx.x * 256 + threadIdx.x;   // 0 .. 2621439 (8 floats each)
    const float4* src;
    unsigned short* dst;
    long off4;
    if (t < 2097152) {            // x region
        src = (const float4*)x;  dst = xb;  off4 = t * 2;
    } else {                      // blocks region
        src = (const float4*)blocks;  dst = bb;  off4 = (t - 2097152) * 2;
    }
    float4 a = src[off4];
    float4 b = src[off4 + 1];
    u16x8 v;
    v[0] = f2bf(a.x); v[1] = f2bf(a.y); v[2] = f2bf(a.z); v[3] = f2bf(a.w);
    v[4] = f2bf(b.x); v[5] = f2bf(b.y); v[6] = f2bf(b.z); v[7] = f2bf(b.w);
    *(u16x8*)(dst + off4 * 4) = v;
}

// --- main: k-split double-buffer, counted vmcnt, 6 wgs/CU ------------------
// LDS layout (ushorts): [A0 | A1 | B0 | B1] = [0, 4096, 8192, 10240], 24KB.
// All tiles LINEAR row-major, 32-col (64B) rows -- conflict-free by parity
// (see header). Staging: lane l of chunk ch writes row ch*16 + (l>>2),
// col-chunk l&3 (global_load_lds dest = uniform base + lane*16).
// Fragment reads: af[r] lane(m,q) <- row w*32+r*16+m, ushort col q*8;
// bfr[c] <- row c*16+m. MFMA 16x16x32: lane m holds 8 contiguous k at q*8.
__global__ __launch_bounds__(256, 6) void bsl_main(
    const unsigned short* __restrict__ xb,   // [4096][4096] bf16
    const unsigned short* __restrict__ blk,  // [1024][64][64] bf16
    const float* __restrict__ bias,
    const int* __restrict__ counts,
    const int* __restrict__ sched,
    const int* __restrict__ csr_pk,
    float* __restrict__ y) {
    __shared__ unsigned short lds[2 * AOFF + 2 * BOFF];   // 24 KB
    __shared__ int pk_s[64];

    const int tid = threadIdx.x;
    const int w = tid >> 6;        // wave 0..3 -> rows [w*32, w*32+32)
    const int l = tid & 63;
    const int m = l & 15;          // MFMA lane coord
    const int q = l >> 4;          // quad -> 8-elem k-chunk within 32-k half

    const int nt = blockIdx.x;     // 32 n-tiles of 128 rows
    const int n0 = nt * NT;
    const int rb = sched[blockIdx.y];   // heavy row-blocks dispatched first
    const int cnt = counts[rb] < 64 ? counts[rb] : 64;
    const int T = cnt * 2;         // half-steps

    // cache pk list in LDS: in-loop reads become ds_read (lgkmcnt), keeping
    // the in-loop vmcnt population = exactly the 3 stage instrs per wave.
    if (tid < cnt) pk_s[tid] = csr_pk[rb * PK_STRIDE + tid];
    __syncthreads();

    // staging lane constants (LINEAR: no swizzle)
    const int lrow = l >> 2;                    // 0..15 row within 1KB chunk
    const int lcc  = l & 3;                     // 16B col-chunk
    const unsigned short* xsrc =
        xb + (size_t)(n0 + lrow) * IN_DIM + lcc * 8;
    const unsigned short* bsrc =
        blk + (size_t)(w * 16 + lrow) * 64 + lcc * 8;

    f32x4 acc[2][4];
#pragma unroll
    for (int r = 0; r < 2; ++r)
#pragma unroll
        for (int c = 0; c < 4; ++c) acc[r][c] = (f32x4){0.f, 0.f, 0.f, 0.f};

    // stage half-step (pk, s) into buffer bufsel: 3 global_load_lds per wave
    auto stage = [&](int bufsel, int pk, int s) {
        const int k  = pk >> 6;
        const int ci = pk & 63;
        // A half: 128 rows x 32 cols = 8 chunks of 1KB; wave w: chunks w, w+4
        const unsigned short* xs = xsrc + ci * 64 + s * 32;
        unsigned short* ad = (unsigned short*)lds + bufsel * AOFF;
#pragma unroll
        for (int i = 0; i < 2; ++i) {
            const int ch = i * 4 + w;
            async_copy16(xs + (size_t)(ch * 16) * IN_DIM, ad + ch * 512);
        }
        // B half: 64 rows x 32 cols = 4 chunks; wave w: chunk w
        async_copy16(bsrc + (size_t)k * 4096 + s * 32,
                     (unsigned short*)lds + 2 * AOFF + bufsel * BOFF + w * 512);
    };

    auto compute = [&](int bufsel) {
        const unsigned short* aC = lds + bufsel * AOFF;
        const unsigned short* bC = lds + 2 * AOFF + bufsel * BOFF;
        bf16x8 af[2], bfr[4];
#pragma unroll
        for (int r = 0; r < 2; ++r)
            af[r] = *(const bf16x8*)(aC + (w * 32 + r * 16 + m) * 32 + q * 8);
#pragma unroll
        for (int c = 0; c < 4; ++c)
            bfr[c] = *(const bf16x8*)(bC + (c * 16 + m) * 32 + q * 8);
#pragma unroll
        for (int r = 0; r < 2; ++r)
#pragma unroll
            for (int c = 0; c < 4; ++c)
                acc[r][c] = __builtin_amdgcn_mfma_f32_16x16x32_bf16(
                    af[r], bfr[c], acc[r][c], 0, 0, 0);
    };

    // ---- counted-vmcnt 2-phase pipeline (T4: never vmcnt(0) in-loop) ----
    if (T > 0) {
        stage(0, pk_s[0], 0);
        int bufsel = 0;
        for (int t = 0; t < T - 1; ++t) {
            const int pk1 = pk_s[(t + 1) >> 1];
            stage(bufsel ^ 1, pk1, (t + 1) & 1);          // +3 vmem in flight
            asm volatile("s_waitcnt vmcnt(3)" ::: "memory"); // stage(t) landed
            __builtin_amdgcn_s_barrier();                  // all waves' too
            compute(bufsel);
            __builtin_amdgcn_s_barrier();  // buf reads done -> next overwrite ok
            bufsel ^= 1;
        }
        asm volatile("s_waitcnt vmcnt(0)" ::: "memory");   // tail drain (once)
        __builtin_amdgcn_s_barrier();
        compute(bufsel);
    }

    // epilogue: C/D layout col=lane&15, row=q*4+e (harness-verified r1-r7);
    // cnt==0 row-blocks still write bias (acc stays zero).
    const int colbase = rb * 64;
#pragma unroll
    for (int c = 0; c < 4; ++c) {
        const float bv = bias[colbase + c * 16 + m];
#pragma unroll
        for (int r = 0; r < 2; ++r) {
            const int rowb = n0 + w * 32 + r * 16 + q * 4;
#pragma unroll
            for (int e = 0; e < 4; ++e) {
                y[(size_t)(rowb + e) * OUT_DIM + colbase + c * 16 + m] =
                    acc[r][c][e] + bv;
            }
        }
    }
}

// ---------------------------------------------------------------------------
extern "C" void kernel_launch(void* const* d_in, const int* in_sizes, int n_in,
                              void* d_out, int out_size, void* d_ws, size_t ws_size,
                              hipStream_t stream) {
    const float* x      = (const float*)d_in[0];
    const float* blocks = (const float*)d_in[1];
    const float* bias   = (const float*)d_in[2];
    const int* row_idx  = (const int*)d_in[3];
    const int* col_idx  = (const int*)d_in[4];
    float* y = (float*)d_out;

    // ws layout: x_bf16 (32MB) | blocks_bf16 (8MB) | counts(64) | sched(64) |
    //            pad | csr_pk (64*PK_STRIDE ints)
    const size_t base = 41943040u;   // 40 MB
    unsigned short* xb = (unsigned short*)d_ws;
    unsigned short* bb = xb + (size_t)N_ROWS * IN_DIM;
    int* counts = (int*)((char*)d_ws + base);
    int* sched  = counts + 64;
    int* csr_pk = (int*)((char*)d_ws + base + 1024);
    if (ws_size < base + 1024 + (size_t)64 * PK_STRIDE * 4) return;

    hipLaunchKernelGGL(bsl_prep, dim3(10241), dim3(256), 0, stream,
                       x, blocks, xb, bb, row_idx, col_idx, counts, sched, csr_pk);
    hipLaunchKernelGGL(bsl_main, dim3(32, 64), dim3(256), 0, stream,
                       xb, bb, bias, counts, sched, csr_pk, y);
}